// Round 1
// baseline (212.449 us; speedup 1.0000x reference)
//
#include <hip/hip_runtime.h>

#define B_  8
#define C_  128
#define H_  96
#define W_  160
#define HWp (H_ * W_)   // 15360 = one channel plane
#define PADY 4
#define HP  104         // H_ + 2*PADY
#define WP  176         // W_ + 16: halo (+8) plus slack so the 32-wide DMA window never goes OOB

typedef short  short8  __attribute__((ext_vector_type(8)));
typedef float  floatx4 __attribute__((ext_vector_type(4)));

// round-to-nearest-even fp32 -> bf16, packed pair (a low 16, b high 16)
__device__ __forceinline__ unsigned pk_bf16(float a, float b) {
    unsigned ua = __float_as_uint(a);
    unsigned ub = __float_as_uint(b);
    ua = (ua + 0x7FFFu + ((ua >> 16) & 1u)) >> 16;
    ub = (ub + 0x7FFFu + ((ub >> 16) & 1u)) & 0xFFFF0000u;
    return ua | ub;
}

// async 16B-per-lane global->LDS DMA. LDS dest: wave-uniform base + lane*16.
// Global src: per-lane address (this is what lets us deposit fragment-order records).
__device__ __forceinline__ void gload_lds16(const void* g, void* l) {
    __builtin_amdgcn_global_load_lds(
        (const __attribute__((address_space(1))) unsigned int*)g,
        (__attribute__((address_space(3))) unsigned int*)l, 16, 0, 0);
}

// ---------------------------------------------------------------------------
// Pass 1: two[b][c][y][x] fp32  ->  two_t[b][y+4][x+4][c] bf16, zero-padded.
// Block = (b, ypad, c-half 64). Reads full 640B rows, writes 1KB-contiguous.
// ---------------------------------------------------------------------------
__global__ __launch_bounds__(512, 2)
void prep_two(const float* __restrict__ two, unsigned short* __restrict__ two_t) {
    __shared__ float lds[W_][68];    // [x][c_local]; stride 68 keeps 16B alignment, spreads banks

    const int id    = blockIdx.x;
    const int b     = id & 7;             // one batch per XCD
    const int r     = id >> 3;            // 0..207
    const int ypad  = r % HP;
    const int chalf = r / HP;             // 0..1
    const int tid   = threadIdx.x;

    unsigned short* dst = two_t + (size_t)(b * HP + ypad) * WP * C_ + chalf * 64;

    if (ypad < PADY || ypad >= PADY + H_) {       // border rows: zeros (block-uniform path)
        const uint4 z{0u, 0u, 0u, 0u};
        #pragma unroll
        for (int i = 0; i < 3; ++i) {
            const int g = tid + i * 512;          // granule = (x, cg): 16B = 8 consecutive c
            if (g < WP * 8) {
                const int x = g >> 3, cg = g & 7;
                *reinterpret_cast<uint4*>(dst + (size_t)x * C_ + cg * 8) = z;
            }
        }
        return;
    }

    const int y  = ypad - PADY;
    const int c2 = tid >> 3;              // 0..63 local channel
    const int q  = tid & 7;               // x-quad slot
    const float* src = two + ((size_t)(b * C_ + chalf * 64 + c2) * H_ + y) * W_;
    #pragma unroll
    for (int j = 0; j < 5; ++j) {
        const int quad = j * 8 + q;       // 0..39 -> x = quad*4 (contiguous 128B per row per j)
        const floatx4 v = *reinterpret_cast<const floatx4*>(&src[quad * 4]);
        lds[quad * 4 + 0][c2] = v[0];
        lds[quad * 4 + 1][c2] = v[1];
        lds[quad * 4 + 2][c2] = v[2];
        lds[quad * 4 + 3][c2] = v[3];
    }
    __syncthreads();
    #pragma unroll
    for (int i = 0; i < 3; ++i) {
        const int g = tid + i * 512;
        if (g < WP * 8) {
            const int x  = g >> 3, cg = g & 7;
            const int xs = x - 4;
            uint4 v{0u, 0u, 0u, 0u};
            if ((unsigned)xs < (unsigned)W_) {
                const floatx4 f0 = *reinterpret_cast<const floatx4*>(&lds[xs][cg * 8 + 0]);
                const floatx4 f1 = *reinterpret_cast<const floatx4*>(&lds[xs][cg * 8 + 4]);
                v.x = pk_bf16(f0[0], f0[1]);
                v.y = pk_bf16(f0[2], f0[3]);
                v.z = pk_bf16(f1[0], f1[1]);
                v.w = pk_bf16(f1[2], f1[3]);
            }
            // lanes cover cg fastest -> 1KB contiguous per wave store
            *reinterpret_cast<uint4*>(dst + (size_t)x * C_ + cg * 8) = v;
        }
    }
}

// ---------------------------------------------------------------------------
// Pass 2: band-GEMM correlation. `two` staged by async global_load_lds DMA
// (bf16 records straight from two_t), `one` by the proven 8-load register
// path. Raw barriers + counted vmcnt: loads stay in flight across barriers.
// ---------------------------------------------------------------------------
__global__ __launch_bounds__(512, 4)
void corr2_kernel(const float* __restrict__ one, const unsigned short* __restrict__ two_t,
                  float* __restrict__ out) {
    __shared__ uint4 two_q[2][16 * 128];   // 32 KB x2: [ry16][ct2*64 + kg4*16 + n16]
    __shared__ uint4 one_q[2][8 * 64];     //  8 KB x2: [y8][kg4*16 + x16]   -> 80 KB total

    const int id = blockIdx.x;
    const int b  = id & 7;            // one batch per XCD
    const int jj = id >> 3;           // 0..119
    const int yt = jj % 12;
    const int xt = jj / 12;
    const int y0 = yt * 8;
    const int x0 = xt * 16;

    const int tid  = threadIdx.x;
    const int lane = tid & 63;
    const int w    = tid >> 6;        // wave id = y-row within tile
    const int kq   = lane >> 4;       // 0..3
    const int nn   = lane & 15;

    // ---- `one` staging thread map (register path): thread -> (x16, y8, kg4) ----
    const int o_xl  = tid & 15;
    const int o_yl  = (tid >> 4) & 7;
    const int o_kg  = tid >> 7;
    const int o_rec = o_yl * 64 + o_kg * 16 + o_xl;
    const float* o_base = one + ((size_t)(b * C_ + 8 * o_kg) * H_ + (y0 + o_yl)) * W_ + (x0 + o_xl);

    // ---- `two` DMA map: wave w covers instrs ii = w*4+q -> (ry = ii>>1, ct = ii&1);
    //      lane (kg,n) fetches 16B = 8 channels at (y0+ry, x0+ct*16+n) [padded coords]
    int toff[4];
    #pragma unroll
    for (int q = 0; q < 4; ++q) {
        const int ii = w * 4 + q;
        const int ry = ii >> 1, ct = ii & 1;
        toff[q] = ((b * HP + y0 + ry) * WP + (x0 + ct * 16 + nn)) * C_ + kq * 8;
    }

    float ro0[8], ro1[8];             // `one` raw ping-pong

    #define ISSUE_DMA(ck, buf) do {                                              \
        _Pragma("unroll")                                                        \
        for (int q = 0; q < 4; ++q)                                              \
            gload_lds16(two_t + toff[q] + (ck) * 32,                             \
                        &two_q[buf][(w * 4 + q) * 64]);                          \
    } while (0)

    #define ISSUE_ONE(ck, ro) do {                                              \
        const float* p1 = o_base + (size_t)((ck) * 32) * HWp;                    \
        _Pragma("unroll")                                                        \
        for (int i = 0; i < 8; ++i) ro[i] = p1[(size_t)i * HWp];                 \
    } while (0)

    #define COMMIT_ONE(ro, buf) do {                                            \
        uint4 v;                                                                 \
        v.x = pk_bf16(ro[0], ro[1]);                                             \
        v.y = pk_bf16(ro[2], ro[3]);                                             \
        v.z = pk_bf16(ro[4], ro[5]);                                             \
        v.w = pk_bf16(ro[6], ro[7]);                                             \
        one_q[buf][o_rec] = v;                                                   \
    } while (0)

    // raw barrier: drain own LDS ops, do NOT drain vmcnt (DMA stays in flight)
    #define BAR() asm volatile("s_waitcnt lgkmcnt(0)\n\ts_barrier" ::: "memory")

    floatx4 acc[9][2];
    #pragma unroll
    for (int dy = 0; dy < 9; ++dy) {
        acc[dy][0] = floatx4{0.f, 0.f, 0.f, 0.f};
        acc[dy][1] = floatx4{0.f, 0.f, 0.f, 0.f};
    }

    // ---- prologue: 2 chunks in flight (12 vmem ops each: 4 DMA + 8 one-loads) ----
    ISSUE_DMA(0, 0); ISSUE_ONE(0, ro0);
    ISSUE_DMA(1, 1); ISSUE_ONE(1, ro1);

    #pragma unroll
    for (int ck = 0; ck < 4; ++ck) {
        const int cur = ck & 1;
        // drain chunk ck's 12 ops; keep chunk ck+1's 12 in flight (never vmcnt(0) mid-loop)
        if (ck < 3) asm volatile("s_waitcnt vmcnt(12)" ::: "memory");
        else        asm volatile("s_waitcnt vmcnt(0)"  ::: "memory");

        if (cur == 0) COMMIT_ONE(ro0, 0); else COMMIT_ONE(ro1, 1);
        BAR();   // one_q committed + everyone's DMA(ck) landed -> safe to read

        const short8 A = *reinterpret_cast<const short8*>(&one_q[cur][w * 64 + lane]);
        #pragma unroll
        for (int dy = 0; dy < 9; ++dy) {
            const int ry = w + dy;
            const short8 Bt0 = *reinterpret_cast<const short8*>(&two_q[cur][ry * 128 + lane]);
            const short8 Bt1 = *reinterpret_cast<const short8*>(&two_q[cur][ry * 128 + 64 + lane]);
            acc[dy][0] = __builtin_amdgcn_mfma_f32_16x16x32_bf16(A, Bt0, acc[dy][0], 0, 0, 0);
            acc[dy][1] = __builtin_amdgcn_mfma_f32_16x16x32_bf16(A, Bt1, acc[dy][1], 0, 0, 0);
        }
        BAR();   // all reads of buf[cur] complete before anyone refills it

        if (ck < 2) {
            ISSUE_DMA(ck + 2, cur);
            if (cur == 0) ISSUE_ONE(ck + 2, ro0); else ISSUE_ONE(ck + 2, ro1);
        }
    }

    // ---- epilogue: D[m=quad*4+r][n=lane&15]; ct0: dx=n-m, ct1: dx=n-m+16 ----
    const int  y  = y0 + w;
    const float scale = 1.0f / (float)C_;
    #pragma unroll
    for (int dy = 0; dy < 9; ++dy) {
        #pragma unroll
        for (int ct = 0; ct < 2; ++ct) {
            floatx4 v = acc[dy][ct];
            #pragma unroll
            for (int r = 0; r < 4; ++r) {
                int m  = kq * 4 + r;
                int dx = nn - m + ct * 16;
                if ((unsigned)dx <= 8u) {
                    size_t o = ((size_t)(b * 81 + dy * 9 + dx) * H_ + y) * W_ + (x0 + m);
                    out[o] = v[r] * scale;
                }
            }
        }
    }
    #undef ISSUE_DMA
    #undef ISSUE_ONE
    #undef COMMIT_ONE
    #undef BAR
}

// ---------------------------------------------------------------------------
// Fallback: previous harness-verified single-pass kernel (used if ws too small)
// ---------------------------------------------------------------------------
__global__ __launch_bounds__(512, 2)
void corr_kernel(const float* __restrict__ one, const float* __restrict__ two,
                 float* __restrict__ out) {
    __shared__ uint4 one_q[2][8 * 64];
    __shared__ uint4 two_q[2][16 * 128];

    const int id = blockIdx.x;
    const int b  = id & 7;
    const int jj = id >> 3;
    const int yt = jj % 12;
    const int xt = jj / 12;
    const int y0 = yt * 8;
    const int x0 = xt * 16;

    const int tid  = threadIdx.x;
    const int lane = tid & 63;
    const int w    = tid >> 6;

    const int o_xl  = tid & 15;
    const int o_yl  = (tid >> 4) & 7;
    const int o_kg  = tid >> 7;
    const int o_rec = o_yl * 64 + o_kg * 16 + o_xl;

    const int t_cx  = tid & 31;
    const int t_ry  = tid >> 5;
    const int t_y   = y0 - 4 + t_ry;
    const int t_gx  = x0 - 4 + t_cx;
    const bool t_valid = ((unsigned)t_y < H_) && ((unsigned)t_gx < W_) && (t_cx < 24);
    const int t_rec = t_ry * 128 + (t_cx >> 4) * 64 + (t_cx & 15);

    const float* o_base = one + ((size_t)(b * C_ + 8 * o_kg) * H_ + (y0 + o_yl)) * W_ + (x0 + o_xl);
    const float* t_base = two + ((size_t)(b * C_) * H_ + t_y) * W_ + t_gx;

    float ro[8];
    float rt[32];

    floatx4 acc[9][2];
    #pragma unroll
    for (int dy = 0; dy < 9; ++dy) {
        acc[dy][0] = floatx4{0.f, 0.f, 0.f, 0.f};
        acc[dy][1] = floatx4{0.f, 0.f, 0.f, 0.f};
    }

    {
        const float* p1 = o_base;
        #pragma unroll
        for (int i = 0; i < 8; ++i) ro[i] = p1[(size_t)i * HWp];
        if (t_valid) {
            const float* p2 = t_base;
            #pragma unroll
            for (int i = 0; i < 32; ++i) rt[i] = p2[(size_t)i * HWp];
        } else {
            #pragma unroll
            for (int i = 0; i < 32; ++i) rt[i] = 0.f;
        }
    }

    #pragma unroll
    for (int ck = 0; ck < 4; ++ck) {
        const int bf = ck & 1;
        {
            uint4 v;
            v.x = pk_bf16(ro[0], ro[1]);
            v.y = pk_bf16(ro[2], ro[3]);
            v.z = pk_bf16(ro[4], ro[5]);
            v.w = pk_bf16(ro[6], ro[7]);
            one_q[bf][o_rec] = v;
            #pragma unroll
            for (int kg = 0; kg < 4; ++kg) {
                uint4 u;
                u.x = pk_bf16(rt[kg * 8 + 0], rt[kg * 8 + 1]);
                u.y = pk_bf16(rt[kg * 8 + 2], rt[kg * 8 + 3]);
                u.z = pk_bf16(rt[kg * 8 + 4], rt[kg * 8 + 5]);
                u.w = pk_bf16(rt[kg * 8 + 6], rt[kg * 8 + 7]);
                two_q[bf][t_rec + kg * 16] = u;
            }
        }
        __syncthreads();

        if (ck < 3) {
            const float* p1 = o_base + (size_t)((ck + 1) * 32) * HWp;
            #pragma unroll
            for (int i = 0; i < 8; ++i) ro[i] = p1[(size_t)i * HWp];
            if (t_valid) {
                const float* p2 = t_base + (size_t)((ck + 1) * 32) * HWp;
                #pragma unroll
                for (int i = 0; i < 32; ++i) rt[i] = p2[(size_t)i * HWp];
            }
        }

        const short8 A = *reinterpret_cast<const short8*>(&one_q[bf][w * 64 + lane]);
        #pragma unroll
        for (int dy = 0; dy < 9; ++dy) {
            const int ry = w + dy;
            const short8 Bt0 = *reinterpret_cast<const short8*>(&two_q[bf][ry * 128 + lane]);
            const short8 Bt1 = *reinterpret_cast<const short8*>(&two_q[bf][ry * 128 + 64 + lane]);
            acc[dy][0] = __builtin_amdgcn_mfma_f32_16x16x32_bf16(A, Bt0, acc[dy][0], 0, 0, 0);
            acc[dy][1] = __builtin_amdgcn_mfma_f32_16x16x32_bf16(A, Bt1, acc[dy][1], 0, 0, 0);
        }
    }

    const int  qq = lane >> 4;
    const int  nn2 = lane & 15;
    const int  y  = y0 + w;
    const float scale = 1.0f / (float)C_;
    #pragma unroll
    for (int dy = 0; dy < 9; ++dy) {
        #pragma unroll
        for (int ct = 0; ct < 2; ++ct) {
            floatx4 v = acc[dy][ct];
            #pragma unroll
            for (int r = 0; r < 4; ++r) {
                int m  = qq * 4 + r;
                int dx = nn2 - m + ct * 16;
                if ((unsigned)dx <= 8u) {
                    size_t o = ((size_t)(b * 81 + dy * 9 + dx) * H_ + y) * W_ + (x0 + m);
                    out[o] = v[r] * scale;
                }
            }
        }
    }
}

extern "C" void kernel_launch(void* const* d_in, const int* in_sizes, int n_in,
                              void* d_out, int out_size, void* d_ws, size_t ws_size,
                              hipStream_t stream) {
    const float* one = (const float*)d_in[0];
    const float* two = (const float*)d_in[1];
    float* out = (float*)d_out;
    const size_t need = (size_t)B_ * HP * WP * C_ * 2;   // 37,486,592 B bf16 padded-transposed `two`
    if (d_ws != nullptr && ws_size >= need) {
        unsigned short* two_t = (unsigned short*)d_ws;
        // pass 1: 8 b * 104 ypad * 2 c-halves = 1664 blocks
        prep_two<<<dim3(1664), dim3(512), 0, stream>>>(two, two_t);
        // pass 2: 8 batches * 12 y-tiles * 10 x-tiles = 960 blocks
        corr2_kernel<<<dim3(960), dim3(512), 0, stream>>>(one, two_t, out);
    } else {
        corr_kernel<<<dim3(960), dim3(512), 0, stream>>>(one, two, out);
    }
}

// Round 3
// 194.840 us; speedup vs baseline: 1.0904x; 1.0904x over previous
//
#include <hip/hip_runtime.h>

#define B_  8
#define C_  128
#define H_  96
#define W_  160
#define HWp (H_ * W_)   // 15360 = one channel plane
#define PADY 4
#define HP  104         // H_ + 2*PADY
#define WP  176         // W_ + 16: halo (+8) plus slack so the 32-wide DMA window never goes OOB

typedef short  short8  __attribute__((ext_vector_type(8)));
typedef float  floatx4 __attribute__((ext_vector_type(4)));

// round-to-nearest-even fp32 -> bf16, packed pair (a low 16, b high 16)
__device__ __forceinline__ unsigned pk_bf16(float a, float b) {
    unsigned ua = __float_as_uint(a);
    unsigned ub = __float_as_uint(b);
    ua = (ua + 0x7FFFu + ((ua >> 16) & 1u)) >> 16;
    ub = (ub + 0x7FFFu + ((ub >> 16) & 1u)) & 0xFFFF0000u;
    return ua | ub;
}

// async 16B-per-lane global->LDS DMA (offset arg must be a literal constant,
// so chunk offsets are folded into the global pointer at the call site).
__device__ __forceinline__ void gload_lds16(const void* g, void* l) {
    __builtin_amdgcn_global_load_lds(
        (const __attribute__((address_space(1))) unsigned int*)g,
        (__attribute__((address_space(3))) unsigned int*)l, 16, 0, 0);
}

// ---------------------------------------------------------------------------
// Prep: fp32 NCHW -> bf16 NHWC for both tensors (two with zero-padded halo).
//   id < 1664 : two[b][c][y][x] -> two_t[b][y+4][x+4][c]   (zero-padded)
//   id >=1664 : one[b][c][y][x] -> one_t[b][y][x][c]
// One launch so both transposes overlap on the device.
// ---------------------------------------------------------------------------
__global__ __launch_bounds__(512, 2)
void prep_kernel(const float* __restrict__ two, const float* __restrict__ one,
                 unsigned short* __restrict__ two_t, unsigned short* __restrict__ one_t) {
    __shared__ float lds[W_][68];    // [x][c_local]; stride 68 keeps 16B align, spreads banks

    const int id  = blockIdx.x;
    const int tid = threadIdx.x;

    if (id < 1664) {
        // ----- two path -----
        const int b     = id & 7;
        const int r     = id >> 3;            // 0..207
        const int ypad  = r % HP;
        const int chalf = r / HP;             // 0..1
        unsigned short* dst = two_t + (size_t)(b * HP + ypad) * WP * C_ + chalf * 64;

        if (ypad < PADY || ypad >= PADY + H_) {       // border rows: zeros
            const uint4 z{0u, 0u, 0u, 0u};
            #pragma unroll
            for (int i = 0; i < 3; ++i) {
                const int g = tid + i * 512;          // granule = (x, cg): 16B = 8 c
                if (g < WP * 8) {
                    const int x = g >> 3, cg = g & 7;
                    *reinterpret_cast<uint4*>(dst + (size_t)x * C_ + cg * 8) = z;
                }
            }
            return;
        }

        const int y  = ypad - PADY;
        const int c2 = tid >> 3;              // 0..63 local channel
        const int q  = tid & 7;               // x-quad slot
        const float* src = two + ((size_t)(b * C_ + chalf * 64 + c2) * H_ + y) * W_;
        #pragma unroll
        for (int j = 0; j < 5; ++j) {
            const int quad = j * 8 + q;       // x = quad*4
            const floatx4 v = *reinterpret_cast<const floatx4*>(&src[quad * 4]);
            lds[quad * 4 + 0][c2] = v[0];
            lds[quad * 4 + 1][c2] = v[1];
            lds[quad * 4 + 2][c2] = v[2];
            lds[quad * 4 + 3][c2] = v[3];
        }
        __syncthreads();
        #pragma unroll
        for (int i = 0; i < 3; ++i) {
            const int g = tid + i * 512;
            if (g < WP * 8) {
                const int x  = g >> 3, cg = g & 7;
                const int xs = x - 4;
                uint4 v{0u, 0u, 0u, 0u};
                if ((unsigned)xs < (unsigned)W_) {
                    const floatx4 f0 = *reinterpret_cast<const floatx4*>(&lds[xs][cg * 8 + 0]);
                    const floatx4 f1 = *reinterpret_cast<const floatx4*>(&lds[xs][cg * 8 + 4]);
                    v.x = pk_bf16(f0[0], f0[1]);
                    v.y = pk_bf16(f0[2], f0[3]);
                    v.z = pk_bf16(f1[0], f1[1]);
                    v.w = pk_bf16(f1[2], f1[3]);
                }
                *reinterpret_cast<uint4*>(dst + (size_t)x * C_ + cg * 8) = v;
            }
        }
    } else {
        // ----- one path (no padding) -----
        const int gidx  = id - 1664;
        const int b     = gidx & 7;
        const int r     = gidx >> 3;          // 0..191
        const int y     = r % H_;
        const int chalf = r / H_;             // 0..1
        unsigned short* dst = one_t + (size_t)(b * H_ + y) * W_ * C_ + chalf * 64;

        const int c2 = tid >> 3;
        const int q  = tid & 7;
        const float* src = one + ((size_t)(b * C_ + chalf * 64 + c2) * H_ + y) * W_;
        #pragma unroll
        for (int j = 0; j < 5; ++j) {
            const int quad = j * 8 + q;
            const floatx4 v = *reinterpret_cast<const floatx4*>(&src[quad * 4]);
            lds[quad * 4 + 0][c2] = v[0];
            lds[quad * 4 + 1][c2] = v[1];
            lds[quad * 4 + 2][c2] = v[2];
            lds[quad * 4 + 3][c2] = v[3];
        }
        __syncthreads();
        #pragma unroll
        for (int i = 0; i < 3; ++i) {
            const int g = tid + i * 512;
            if (g < W_ * 8) {
                const int x  = g >> 3, cg = g & 7;
                const floatx4 f0 = *reinterpret_cast<const floatx4*>(&lds[x][cg * 8 + 0]);
                const floatx4 f1 = *reinterpret_cast<const floatx4*>(&lds[x][cg * 8 + 4]);
                uint4 v;
                v.x = pk_bf16(f0[0], f0[1]);
                v.y = pk_bf16(f0[2], f0[3]);
                v.z = pk_bf16(f1[0], f1[1]);
                v.w = pk_bf16(f1[2], f1[3]);
                *reinterpret_cast<uint4*>(dst + (size_t)x * C_ + cg * 8) = v;
            }
        }
    }
}

// ---------------------------------------------------------------------------
// Pass 2: band-GEMM correlation, pure-DMA staging (both operands via
// global_load_lds from bf16 NHWC), counted vmcnt, raw barriers, coalesced
// LDS-staged epilogue. No register staging, no pack VALU in the loop.
// ---------------------------------------------------------------------------
__global__ __launch_bounds__(512, 4)
void corr2_kernel(const unsigned short* __restrict__ one_t,
                  const unsigned short* __restrict__ two_t,
                  float* __restrict__ out) {
    __shared__ uint4 two_q[2][16 * 128];   // 32 KB x2: [ry16][ct2*64 + kg4*16 + n16]
    __shared__ uint4 one_q[2][8 * 64];     //  8 KB x2: [y8][kg4*16 + x16]  -> 80 KB total

    const int id = blockIdx.x;
    const int b  = id & 7;            // one batch per XCD
    const int jj = id >> 3;           // 0..119
    const int yt = jj % 12;
    const int xt = jj / 12;
    const int y0 = yt * 8;
    const int x0 = xt * 16;

    const int tid  = threadIdx.x;
    const int lane = tid & 63;
    const int w    = tid >> 6;        // wave id = y-row within tile
    const int kq   = lane >> 4;       // 0..3
    const int nn   = lane & 15;

    // ---- DMA source pointers (per-lane) ----
    // one: wave w, lane (kq,nn) -> 8 c at (y0+w, x0+nn); chunk adds ck*32 shorts
    const unsigned short* p_one =
        one_t + ((size_t)((b * H_ + y0 + w) * W_ + x0 + nn)) * C_ + kq * 8;
    // two: wave w covers ii = w*4+q -> (ry = ii>>1, ct = ii&1)
    const unsigned short* p_two[4];
    #pragma unroll
    for (int q = 0; q < 4; ++q) {
        const int ii = w * 4 + q;
        const int ry = ii >> 1, ct = ii & 1;
        p_two[q] = two_t + ((size_t)((b * HP + y0 + ry) * WP + x0 + ct * 16 + nn)) * C_ + kq * 8;
    }

    #define ISSUE(ck, buf) do {                                                  \
        gload_lds16(p_one + (ck) * 32, &one_q[buf][w * 64]);                     \
        _Pragma("unroll")                                                        \
        for (int q = 0; q < 4; ++q)                                              \
            gload_lds16(p_two[q] + (ck) * 32, &two_q[buf][(w * 4 + q) * 64]);    \
    } while (0)

    // raw barrier: drain own LDS ops, do NOT drain vmcnt (DMA stays in flight)
    #define BAR() asm volatile("s_waitcnt lgkmcnt(0)\n\ts_barrier" ::: "memory")

    floatx4 acc[9][2];
    #pragma unroll
    for (int dy = 0; dy < 9; ++dy) {
        acc[dy][0] = floatx4{0.f, 0.f, 0.f, 0.f};
        acc[dy][1] = floatx4{0.f, 0.f, 0.f, 0.f};
    }

    // ---- prologue: 2 chunks in flight (5 vmem ops each) ----
    ISSUE(0, 0);
    ISSUE(1, 1);

    #pragma unroll
    for (int ck = 0; ck < 4; ++ck) {
        const int cur = ck & 1;
        // drain chunk ck's 5 DMAs; keep chunk ck+1's 5 in flight
        if (ck < 3) asm volatile("s_waitcnt vmcnt(5)" ::: "memory");
        else        asm volatile("s_waitcnt vmcnt(0)" ::: "memory");
        BAR();   // all waves' DMAs for chunk ck have landed -> safe to read

        const short8 A = *reinterpret_cast<const short8*>(&one_q[cur][w * 64 + lane]);
        #pragma unroll
        for (int dy = 0; dy < 9; ++dy) {
            const int ry = w + dy;
            const short8 Bt0 = *reinterpret_cast<const short8*>(&two_q[cur][ry * 128 + lane]);
            const short8 Bt1 = *reinterpret_cast<const short8*>(&two_q[cur][ry * 128 + 64 + lane]);
            acc[dy][0] = __builtin_amdgcn_mfma_f32_16x16x32_bf16(A, Bt0, acc[dy][0], 0, 0, 0);
            acc[dy][1] = __builtin_amdgcn_mfma_f32_16x16x32_bf16(A, Bt1, acc[dy][1], 0, 0, 0);
        }
        BAR();   // all reads of buf[cur] complete before anyone refills it

        if (ck < 2) ISSUE(ck + 2, cur);
    }

    // ---- epilogue: stage into LDS (overlaid on dead two_q), store coalesced ----
    __syncthreads();                               // everyone done with two_q
    float* ep = reinterpret_cast<float*>(&two_q[0][0]);   // 81*130*4 = 42 KB < 64 KB
    const float scale = 1.0f / (float)C_;
    #pragma unroll
    for (int dy = 0; dy < 9; ++dy) {
        #pragma unroll
        for (int ct = 0; ct < 2; ++ct) {
            floatx4 v = acc[dy][ct];
            #pragma unroll
            for (int r = 0; r < 4; ++r) {
                const int m  = kq * 4 + r;
                const int dx = nn - m + ct * 16;
                if ((unsigned)dx <= 8u)
                    ep[(dy * 9 + dx) * 130 + w * 16 + m] = v[r] * scale;
            }
        }
    }
    __syncthreads();
    // 81 planes * 128 floats = 10368 dwords; lanes cover x fastest -> full 64B lines
    #pragma unroll
    for (int i = 0; i < 21; ++i) {
        const int g = tid + i * 512;
        if (g < 81 * 128) {
            const int p   = g >> 7;
            const int loc = g & 127;               // yy*16 + xx
            const int yy  = loc >> 4, xx = loc & 15;
            out[((size_t)(b * 81 + p) * H_ + y0 + yy) * W_ + x0 + xx] = ep[p * 130 + loc];
        }
    }
    #undef ISSUE
    #undef BAR
}

// ---------------------------------------------------------------------------
// Fallback: harness-verified single-pass kernel (used if workspace too small)
// ---------------------------------------------------------------------------
__global__ __launch_bounds__(512, 2)
void corr_kernel(const float* __restrict__ one, const float* __restrict__ two,
                 float* __restrict__ out) {
    __shared__ uint4 one_q[2][8 * 64];
    __shared__ uint4 two_q[2][16 * 128];

    const int id = blockIdx.x;
    const int b  = id & 7;
    const int jj = id >> 3;
    const int yt = jj % 12;
    const int xt = jj / 12;
    const int y0 = yt * 8;
    const int x0 = xt * 16;

    const int tid  = threadIdx.x;
    const int lane = tid & 63;
    const int w    = tid >> 6;

    const int o_xl  = tid & 15;
    const int o_yl  = (tid >> 4) & 7;
    const int o_kg  = tid >> 7;
    const int o_rec = o_yl * 64 + o_kg * 16 + o_xl;

    const int t_cx  = tid & 31;
    const int t_ry  = tid >> 5;
    const int t_y   = y0 - 4 + t_ry;
    const int t_gx  = x0 - 4 + t_cx;
    const bool t_valid = ((unsigned)t_y < H_) && ((unsigned)t_gx < W_) && (t_cx < 24);
    const int t_rec = t_ry * 128 + (t_cx >> 4) * 64 + (t_cx & 15);

    const float* o_base = one + ((size_t)(b * C_ + 8 * o_kg) * H_ + (y0 + o_yl)) * W_ + (x0 + o_xl);
    const float* t_base = two + ((size_t)(b * C_) * H_ + t_y) * W_ + t_gx;

    float ro[8];
    float rt[32];

    floatx4 acc[9][2];
    #pragma unroll
    for (int dy = 0; dy < 9; ++dy) {
        acc[dy][0] = floatx4{0.f, 0.f, 0.f, 0.f};
        acc[dy][1] = floatx4{0.f, 0.f, 0.f, 0.f};
    }

    {
        const float* p1 = o_base;
        #pragma unroll
        for (int i = 0; i < 8; ++i) ro[i] = p1[(size_t)i * HWp];
        if (t_valid) {
            const float* p2 = t_base;
            #pragma unroll
            for (int i = 0; i < 32; ++i) rt[i] = p2[(size_t)i * HWp];
        } else {
            #pragma unroll
            for (int i = 0; i < 32; ++i) rt[i] = 0.f;
        }
    }

    #pragma unroll
    for (int ck = 0; ck < 4; ++ck) {
        const int bf = ck & 1;
        {
            uint4 v;
            v.x = pk_bf16(ro[0], ro[1]);
            v.y = pk_bf16(ro[2], ro[3]);
            v.z = pk_bf16(ro[4], ro[5]);
            v.w = pk_bf16(ro[6], ro[7]);
            one_q[bf][o_rec] = v;
            #pragma unroll
            for (int kg = 0; kg < 4; ++kg) {
                uint4 u;
                u.x = pk_bf16(rt[kg * 8 + 0], rt[kg * 8 + 1]);
                u.y = pk_bf16(rt[kg * 8 + 2], rt[kg * 8 + 3]);
                u.z = pk_bf16(rt[kg * 8 + 4], rt[kg * 8 + 5]);
                u.w = pk_bf16(rt[kg * 8 + 6], rt[kg * 8 + 7]);
                two_q[bf][t_rec + kg * 16] = u;
            }
        }
        __syncthreads();

        if (ck < 3) {
            const float* p1 = o_base + (size_t)((ck + 1) * 32) * HWp;
            #pragma unroll
            for (int i = 0; i < 8; ++i) ro[i] = p1[(size_t)i * HWp];
            if (t_valid) {
                const float* p2 = t_base + (size_t)((ck + 1) * 32) * HWp;
                #pragma unroll
                for (int i = 0; i < 32; ++i) rt[i] = p2[(size_t)i * HWp];
            }
        }

        const short8 A = *reinterpret_cast<const short8*>(&one_q[bf][w * 64 + lane]);
        #pragma unroll
        for (int dy = 0; dy < 9; ++dy) {
            const int ry = w + dy;
            const short8 Bt0 = *reinterpret_cast<const short8*>(&two_q[bf][ry * 128 + lane]);
            const short8 Bt1 = *reinterpret_cast<const short8*>(&two_q[bf][ry * 128 + 64 + lane]);
            acc[dy][0] = __builtin_amdgcn_mfma_f32_16x16x32_bf16(A, Bt0, acc[dy][0], 0, 0, 0);
            acc[dy][1] = __builtin_amdgcn_mfma_f32_16x16x32_bf16(A, Bt1, acc[dy][1], 0, 0, 0);
        }
    }

    const int  qq = lane >> 4;
    const int  nn2 = lane & 15;
    const int  y  = y0 + w;
    const float scale = 1.0f / (float)C_;
    #pragma unroll
    for (int dy = 0; dy < 9; ++dy) {
        #pragma unroll
        for (int ct = 0; ct < 2; ++ct) {
            floatx4 v = acc[dy][ct];
            #pragma unroll
            for (int r = 0; r < 4; ++r) {
                int m  = qq * 4 + r;
                int dx = nn2 - m + ct * 16;
                if ((unsigned)dx <= 8u) {
                    size_t o = ((size_t)(b * 81 + dy * 9 + dx) * H_ + y) * W_ + (x0 + m);
                    out[o] = v[r] * scale;
                }
            }
        }
    }
}

extern "C" void kernel_launch(void* const* d_in, const int* in_sizes, int n_in,
                              void* d_out, int out_size, void* d_ws, size_t ws_size,
                              hipStream_t stream) {
    const float* one = (const float*)d_in[0];
    const float* two = (const float*)d_in[1];
    float* out = (float*)d_out;
    const size_t need_two = (size_t)B_ * HP * WP * C_ * 2;            // 37,486,592 B
    const size_t need_one = (size_t)B_ * H_ * W_ * C_ * 2;            // 31,457,280 B
    if (d_ws != nullptr && ws_size >= need_two + need_one) {
        unsigned short* two_t = (unsigned short*)d_ws;
        unsigned short* one_t = two_t + (size_t)B_ * HP * WP * C_;
        // prep: 1664 two-blocks + 1536 one-blocks in one launch
        prep_kernel<<<dim3(3200), dim3(512), 0, stream>>>(two, one, two_t, one_t);
        // corr2: 8 batches * 12 y-tiles * 10 x-tiles = 960 blocks
        corr2_kernel<<<dim3(960), dim3(512), 0, stream>>>(one_t, two_t, out);
    } else {
        corr_kernel<<<dim3(960), dim3(512), 0, stream>>>(one, two, out);
    }
}